// Round 1
// baseline (504.490 us; speedup 1.0000x reference)
//
#include <hip/hip_runtime.h>
#include <cstdint>

// LinearAttention on MI355X (gfx950), fp32 in/out, bf16 MFMA compute.
//
// Algebra: out = (q Wq) @ (swish(mask*(k Wk))^T @ (mask*(v Wv))) @ Wo
//        = q @ [ Wq @ kv @ Wo ]   with kv = pk^T pv  ([B,U,U])
// Pipeline (all NT GEMMs: C[m,n] = sum_k A[m,k]*B[n,k]):
//   tconv: WkT, WvT, WoT (transpose + bf16);  conv: Wq -> bf16
//   G1: pkT[b][u][s] = swish(mask * (key  @ Wk))^T   (A=key fp32, B=WkT)
//   G2: pvT[b][v][s] =        mask * (value@ Wv)^T   (A=value fp32, B=WvT)
//   G3: kvT[b][v][u] = sum_s pvT[v,s]*pkT[u,s]       (A=pvT, B=pkT)
//   S1: Wtmp[b][u][v] = sum_w Wq[u,w]*kvT[v,w]       (A=Wqb, B=kvT)
//   S2: WfT[b][x][u]  = sum_v WoT[x,v]*Wtmp[u,v]     (A=WoT, B=Wtmp)
//   G4: out[b][s][x]  = sum_u q[s,u]*WfT[x,u]        (A=query fp32, B=WfT) -> fp32 d_out

typedef unsigned short u16;
typedef unsigned int   u32;
typedef float  f32x4  __attribute__((ext_vector_type(4)));
typedef __bf16 bf16x8 __attribute__((ext_vector_type(8)));
typedef u32    u32x4  __attribute__((ext_vector_type(4)));
typedef u16    u16x4  __attribute__((ext_vector_type(4)));

__device__ __forceinline__ u16 f2bf(float f) {
  u32 u = __builtin_bit_cast(u32, f);
  u = (u + 0x7FFFu + ((u >> 16) & 1u)) >> 16;   // RNE
  return (u16)u;
}
__device__ __forceinline__ u32 pack2(float a, float b) {
  return (u32)f2bf(a) | ((u32)f2bf(b) << 16);
}

// ---------------------------------------------------------------------------
// NT GEMM, 128x128 tile, BK=64, 4 waves (2x2 of 64x64), mfma_f32_16x16x32_bf16.
// A: [M][K] (fp32 if AF32 else bf16), B: [N][K] bf16. LDS xor-swizzled (T2).
// EPI: 0 = transposed bf16 store, *mask then swish (pkT)
//      1 = transposed bf16 store, *mask              (pvT)
//      2 = plain bf16 store                          (kvT/Wtmp/WfT)
//      3 = plain fp32 store                          (final output)
// For EPI<=1 the transposed-store row stride and the mask stride are M.
// ---------------------------------------------------------------------------
template<int EPI, int AF32>
__global__ __launch_bounds__(256)
void gemm_nt(const void* __restrict__ Aptr, const u16* __restrict__ Bptr,
             void* __restrict__ Cptr, const float* __restrict__ maskp,
             int M, int N, int K, int ldA, int ldB,
             long batchA, long batchB, long batchC)
{
  __shared__ u16 As[128 * 64];
  __shared__ u16 Bs[128 * 64];

  const int t    = threadIdx.x;
  const int z    = blockIdx.z;
  const int m0   = blockIdx.y * 128;
  const int n0   = blockIdx.x * 128;
  const int lane = t & 63;
  const int w    = t >> 6, wr = w >> 1, wc = w & 1;
  const int g    = lane >> 4, r16 = lane & 15;
  const int srow = t >> 3, sk8 = t & 7;                  // staging: 32 rows x 8 chunks
  const int swz_w = (sk8 ^ (srow & 7)) << 4;             // write-side swizzled k-offset
  const int swz_r = (r16 & 7) << 4;                      // read-side xor term

  const float* Af = (const float*)Aptr + (AF32 ? batchA * (long)z : 0);
  const u16*   Ab = (const u16*)Aptr   + (AF32 ? 0 : batchA * (long)z);
  const u16*   Bb = Bptr + batchB * (long)z;

  f32x4 acc[4][4];
  {
    f32x4 z4;
    for (int q = 0; q < 4; ++q) z4[q] = 0.f;
    #pragma unroll
    for (int i = 0; i < 4; ++i)
      #pragma unroll
      for (int j = 0; j < 4; ++j) acc[i][j] = z4;
  }

  f32x4 raf[4][2];   // fp32-A staging regs
  u32x4 ra[4];       // bf16-A staging regs
  u32x4 rb[4];       // B staging regs

  auto LOAD = [&](int kt) {
    const long kcol = (long)kt * 64 + sk8 * 8;
    #pragma unroll
    for (int i = 0; i < 4; ++i) {
      const long arow = m0 + i * 32 + srow;
      if constexpr (AF32) {
        const float* p = Af + arow * (long)ldA + kcol;
        raf[i][0] = *(const f32x4*)p;
        raf[i][1] = *(const f32x4*)(p + 4);
      } else {
        const u16* p = Ab + arow * (long)ldA + kcol;
        ra[i] = *(const u32x4*)p;
      }
      const long brow = n0 + i * 32 + srow;
      rb[i] = *(const u32x4*)(Bb + brow * (long)ldB + kcol);
    }
  };

  auto STORE_LDS = [&]() {
    #pragma unroll
    for (int i = 0; i < 4; ++i) {
      const int off = (i * 32 + srow) * 128 + swz_w;
      if constexpr (AF32) {
        u32x4 v;
        v[0] = pack2(raf[i][0][0], raf[i][0][1]);
        v[1] = pack2(raf[i][0][2], raf[i][0][3]);
        v[2] = pack2(raf[i][1][0], raf[i][1][1]);
        v[3] = pack2(raf[i][1][2], raf[i][1][3]);
        *(u32x4*)((char*)As + off) = v;
      } else {
        *(u32x4*)((char*)As + off) = ra[i];
      }
      *(u32x4*)((char*)Bs + off) = rb[i];
    }
  };

  auto COMPUTE = [&]() {
    #pragma unroll
    for (int kk = 0; kk < 2; ++kk) {
      bf16x8 af[4], bfv[4];
      #pragma unroll
      for (int m = 0; m < 4; ++m) {
        const int row  = wr * 64 + m * 16 + r16;
        const int koff = (((kk * 4 + g) << 4) ^ swz_r);
        af[m] = *(const bf16x8*)((const char*)As + row * 128 + koff);
      }
      #pragma unroll
      for (int n = 0; n < 4; ++n) {
        const int row  = wc * 64 + n * 16 + r16;
        const int koff = (((kk * 4 + g) << 4) ^ swz_r);
        bfv[n] = *(const bf16x8*)((const char*)Bs + row * 128 + koff);
      }
      #pragma unroll
      for (int m = 0; m < 4; ++m)
        #pragma unroll
        for (int n = 0; n < 4; ++n)
          acc[m][n] = __builtin_amdgcn_mfma_f32_16x16x32_bf16(af[m], bfv[n], acc[m][n], 0, 0, 0);
    }
  };

  const int nk = K / 64;
  LOAD(0);
  for (int kt = 0;; ++kt) {
    __syncthreads();             // previous tile's compute done
    STORE_LDS();
    __syncthreads();
    if (kt + 1 < nk) LOAD(kt + 1);   // prefetch next tile under MFMA
    COMPUTE();
    if (kt + 1 >= nk) break;
  }

  // Epilogue. C/D frag mapping (HW-verified): col = lane&15, row = 4*(lane>>4)+j.
  if constexpr (EPI <= 1) {
    u16* C = (u16*)Cptr + batchC * (long)z;
    const float* mz = maskp + (long)z * M;
    #pragma unroll
    for (int m = 0; m < 4; ++m) {
      const int sbase = m0 + wr * 64 + m * 16 + 4 * g;   // s index (4 consecutive via j)
      float mk[4];
      #pragma unroll
      for (int j = 0; j < 4; ++j) mk[j] = mz[sbase + j];
      #pragma unroll
      for (int n = 0; n < 4; ++n) {
        const int col = n0 + wc * 64 + n * 16 + r16;     // projected-feature index
        u16x4 v;
        #pragma unroll
        for (int j = 0; j < 4; ++j) {
          float x = acc[m][n][j] * mk[j];                // mask BEFORE swish (ref order)
          if constexpr (EPI == 0) x = x / (1.f + __expf(-x));
          v[j] = f2bf(x);
        }
        *(u16x4*)(C + (long)col * M + sbase) = v;        // transposed store [feat][s]
      }
    }
  } else if constexpr (EPI == 2) {
    u16* C = (u16*)Cptr + batchC * (long)z;
    #pragma unroll
    for (int m = 0; m < 4; ++m) {
      const int rbase = m0 + wr * 64 + m * 16 + 4 * g;
      #pragma unroll
      for (int n = 0; n < 4; ++n) {
        const int col = n0 + wc * 64 + n * 16 + r16;
        #pragma unroll
        for (int j = 0; j < 4; ++j)
          C[(long)(rbase + j) * N + col] = f2bf(acc[m][n][j]);
      }
    }
  } else {
    float* C = (float*)Cptr + batchC * (long)z;
    #pragma unroll
    for (int m = 0; m < 4; ++m) {
      const int rbase = m0 + wr * 64 + m * 16 + 4 * g;
      #pragma unroll
      for (int n = 0; n < 4; ++n) {
        const int col = n0 + wc * 64 + n * 16 + r16;
        #pragma unroll
        for (int j = 0; j < 4; ++j)
          C[(long)(rbase + j) * N + col] = acc[m][n][j];
      }
    }
  }
}

// 1024x1024 transpose + fp32->bf16 (weights). block (32,8), grid (32,32).
__global__ void tconv_kernel(const float* __restrict__ src, u16* __restrict__ dst)
{
  __shared__ float tile[32][33];
  const int tx = threadIdx.x, ty = threadIdx.y;
  const int c0 = blockIdx.x * 32, r0 = blockIdx.y * 32;
  #pragma unroll
  for (int j = 0; j < 4; ++j)
    tile[ty * 4 + j][tx] = src[(long)(r0 + ty * 4 + j) * 1024 + c0 + tx];
  __syncthreads();
  #pragma unroll
  for (int j = 0; j < 4; ++j)
    dst[(long)(c0 + ty * 4 + j) * 1024 + r0 + tx] = f2bf(tile[tx][ty * 4 + j]);
}

// plain fp32->bf16, 8 elems/thread
__global__ void conv_kernel(const float* __restrict__ src, u16* __restrict__ dst, int n8)
{
  const int i = blockIdx.x * blockDim.x + threadIdx.x;
  if (i < n8) {
    const f32x4 a = *(const f32x4*)(src + (long)i * 8);
    const f32x4 b = *(const f32x4*)(src + (long)i * 8 + 4);
    u32x4 v;
    v[0] = pack2(a[0], a[1]);
    v[1] = pack2(a[2], a[3]);
    v[2] = pack2(b[0], b[1]);
    v[3] = pack2(b[2], b[3]);
    *(u32x4*)(dst + (long)i * 8) = v;
  }
}

extern "C" void kernel_launch(void* const* d_in, const int* in_sizes, int n_in,
                              void* d_out, int out_size, void* d_ws, size_t ws_size,
                              hipStream_t stream)
{
  const float* q    = (const float*)d_in[0];
  const float* k    = (const float*)d_in[1];
  const float* v    = (const float*)d_in[2];
  const float* mask = (const float*)d_in[3];
  const float* Wk   = (const float*)d_in[4];
  const float* Wv   = (const float*)d_in[5];
  const float* Wq   = (const float*)d_in[6];
  const float* Wo   = (const float*)d_in[7];

  const int B = 4, S = 4096, U = 1024;
  const long SU = (long)S * U;     // 4M elems
  const long UU = (long)U * U;     // 1M elems

  char* ws = (char*)d_ws;
  u16* pkT = (u16*)(ws);                       // [B][U][S] bf16, 32MB
  u16* pvT = (u16*)(ws + (32l << 20));         // [B][U][S] bf16, 32MB
  u16* WkT = (u16*)(ws + (64l << 20));         // 2MB each
  u16* WvT = (u16*)(ws + (66l << 20));
  u16* Wqb = (u16*)(ws + (68l << 20));
  u16* WoT = (u16*)(ws + (70l << 20));
  u16* kvT = (u16*)(ws + (72l << 20));         // [B][U][U] bf16, 8MB
  u16* Wtm = (u16*)(ws + (80l << 20));         // 8MB
  u16* WfT = (u16*)(ws + (88l << 20));         // 8MB

  const dim3 blk(256);

  // weight prep
  tconv_kernel<<<dim3(32, 32), dim3(32, 8), 0, stream>>>(Wk, WkT);
  tconv_kernel<<<dim3(32, 32), dim3(32, 8), 0, stream>>>(Wv, WvT);
  tconv_kernel<<<dim3(32, 32), dim3(32, 8), 0, stream>>>(Wo, WoT);
  conv_kernel<<<512, 256, 0, stream>>>(Wq, Wqb, (int)(UU / 8));

  // G1: pkT = swish(mask * (key @ Wk))^T      M=S,N=U,K=U, batched over B
  gemm_nt<0, 1><<<dim3(8, 32, 4), blk, 0, stream>>>(k, WkT, pkT, mask,
      S, U, U, U, U, SU, 0, SU);
  // G2: pvT = (mask * (value @ Wv))^T
  gemm_nt<1, 1><<<dim3(8, 32, 4), blk, 0, stream>>>(v, WvT, pvT, mask,
      S, U, U, U, U, SU, 0, SU);
  // G3: kvT[b][v][u] = sum_s pvT[v,s] * pkT[u,s]   M=N=U, K=S
  gemm_nt<2, 0><<<dim3(8, 8, 4), blk, 0, stream>>>(pvT, pkT, kvT, nullptr,
      U, U, S, S, S, SU, SU, UU);
  // S1: Wtmp[b][u][v] = sum_w Wq[u,w] * kvT[v,w]
  gemm_nt<2, 0><<<dim3(8, 8, 4), blk, 0, stream>>>(Wqb, kvT, Wtm, nullptr,
      U, U, U, U, U, 0, UU, UU);
  // S2: WfT[b][x][u] = sum_v WoT[x,v] * Wtmp[u,v]
  gemm_nt<2, 0><<<dim3(8, 8, 4), blk, 0, stream>>>(WoT, Wtm, WfT, nullptr,
      U, U, U, U, U, 0, UU, UU);
  // G4: out[b][s][x] = sum_u q[s,u] * WfT[x,u]  -> fp32 d_out
  gemm_nt<3, 1><<<dim3(8, 32, 4), blk, 0, stream>>>(q, WfT, d_out, nullptr,
      S, U, U, U, U, SU, UU, SU);
}